// Round 1
// baseline (1518.369 us; speedup 1.0000x reference)
//
#include <hip/hip_runtime.h>
#include <stdint.h>

#define SEQ    32
#define BATCH  64
#define D_IN   37632
#define H1     768
#define H2     100
#define NC     101

#define KSPLIT 32
#define KCH    1176              // D_IN / KSPLIT

#define WOT_LD 104
#define RING   4

// ---- workspace layout, offsets in 4-byte words from ws base ----
#define OFF_WFT   0                                        // [768][768]  WfT[j][k] = Wf_rec[k][j]
#define OFF_WCT   (OFF_WFT + H1*H1)                        // [768][100]  WcT[j][k] = Wc_in[k][j]
#define OFF_WCRT  (OFF_WCT + H1*H2)                        // [100][100]  WcRT[j][k] = Wc_rec[k][j]
#define OFF_WOT   (OFF_WCRT + H2*H2)                       // [100][104]  WoT[j][k] = W_out[k][j]
#define OFF_PART  (((OFF_WOT + H2*WOT_LD) + 127) & ~127)   // [KSPLIT][64][768] GEMM partials
#define OFF_ARR   (((OFF_PART + KSPLIT*BATCH*H1) + 63) & ~63)  // [64][64] ints (1 used/row)
#define OFF_CDN   (OFF_ARR + 64*64)                        // [64][64] ints
#define OFF_ZF    (OFF_CDN + 64*64)                        // [64][RING][32] u32 spike ring
// end = OFF_ZF + 64*RING*32  ≈ 2.28M words ≈ 9.2 MB

// =============== kernel A: transposes + counter zeroing ===============
__global__ __launch_bounds__(256) void prep_kernel(
    const float* __restrict__ Wf_rec, const float* __restrict__ Wc_in,
    const float* __restrict__ Wc_rec, const float* __restrict__ W_out,
    float* __restrict__ ws)
{
  const int bid = blockIdx.x, t = threadIdx.x;
  if (bid < 144) {
    // 64x64 tiled transpose of Wf_rec (768x768)
    __shared__ float tile[64][65];
    const int tr = bid / 12, tc = bid % 12;
    for (int i = t; i < 4096; i += 256) {
      const int r = i >> 6, c = i & 63;
      tile[r][c] = Wf_rec[(tr*64 + r)*H1 + (tc*64 + c)];
    }
    __syncthreads();
    float* WfT = ws + OFF_WFT;
    for (int i = t; i < 4096; i += 256) {
      const int c = i >> 6, r = i & 63;
      WfT[(tc*64 + c)*H1 + (tr*64 + r)] = tile[r][c];
    }
  } else if (bid < 160) {
    // small transposes (L2-resident, naive)
    const int NA = H1*H2;                 // WcT elements
    const int NB = H2*H2;                 // WcRT elements
    const int NT = NA + NB + H2*NC;       // + WoT elements
    for (int idx = (bid-144)*256 + t; idx < NT; idx += 16*256) {
      if (idx < NA) {
        const int j = idx / H2, k = idx % H2;
        ws[OFF_WCT + idx] = Wc_in[k*H1 + j];
      } else if (idx < NA + NB) {
        const int q = idx - NA; const int j = q / H2, k = q % H2;
        ws[OFF_WCRT + q] = Wc_rec[k*H2 + j];
      } else {
        const int q = idx - NA - NB; const int j = q / NC, k = q % NC;
        ws[OFF_WOT + j*WOT_LD + k] = W_out[k*H2 + j];
      }
    }
  } else {
    // zero arrive / c_done counters (ws is poisoned 0xAA each launch)
    uint32_t* w = (uint32_t*)ws;
    for (int i = t; i < 64*64*2; i += 256) w[OFF_ARR + i] = 0u;
  }
}

// =============== kernel B: in_f = x @ Wf_in^T (K-split partials) ===============
__global__ __launch_bounds__(256) void gemm_inf(
    const float* __restrict__ x, const float* __restrict__ Wf,
    float* __restrict__ ws)
{
  const int bid = blockIdx.x;
  const int kt = bid % 12;     // which 64-column tile of H1
  const int kc = bid / 12;     // which K-chunk (KCH=1176)
  const int t  = threadIdx.x;
  const int klane = t & 15, blane = t >> 4;
  const int j0 = kc * KCH;

  int bs[4], ks[4];
  #pragma unroll
  for (int u = 0; u < 4; ++u) { bs[u] = blane + 16*u; ks[u] = kt*64 + klane + 16*u; }

  float acc[4][4];
  #pragma unroll
  for (int a = 0; a < 4; ++a)
    #pragma unroll
    for (int b = 0; b < 4; ++b) acc[a][b] = 0.f;

  const float4* xp[4]; const float4* wp[4];
  #pragma unroll
  for (int u = 0; u < 4; ++u) {
    xp[u] = (const float4*)(x  + (size_t)bs[u]*D_IN + j0);
    wp[u] = (const float4*)(Wf + (size_t)ks[u]*D_IN + j0);
  }

  #pragma unroll 2
  for (int j4 = 0; j4 < KCH/4; ++j4) {
    float4 xv[4], wv[4];
    #pragma unroll
    for (int u = 0; u < 4; ++u) xv[u] = xp[u][j4];
    #pragma unroll
    for (int u = 0; u < 4; ++u) wv[u] = wp[u][j4];
    #pragma unroll
    for (int a = 0; a < 4; ++a)
      #pragma unroll
      for (int b = 0; b < 4; ++b) {
        acc[a][b] = fmaf(xv[a].x, wv[b].x, acc[a][b]);
        acc[a][b] = fmaf(xv[a].y, wv[b].y, acc[a][b]);
        acc[a][b] = fmaf(xv[a].z, wv[b].z, acc[a][b]);
        acc[a][b] = fmaf(xv[a].w, wv[b].w, acc[a][b]);
      }
  }

  float* part = ws + OFF_PART + (size_t)kc*(BATCH*H1);
  #pragma unroll
  for (int a = 0; a < 4; ++a)
    #pragma unroll
    for (int b = 0; b < 4; ++b)
      part[bs[a]*H1 + ks[b]] = acc[a][b];
}

// =============== kernel C: the 32-step scan ===============
__device__ __forceinline__ int atomic_load_acq(const int* p) {
  return __hip_atomic_load(p, __ATOMIC_ACQUIRE, __HIP_MEMORY_SCOPE_AGENT);
}

__global__ __launch_bounds__(128) void scan_kernel(
    float* __restrict__ ws, float* __restrict__ out)
{
  const int bid = blockIdx.x, t = threadIdx.x;
  const float* WfT = ws + OFF_WFT;
  uint32_t* ring_all = (uint32_t*)ws + OFF_ZF;
  int* arr_all = (int*)ws + OFF_ARR;
  int* cdn_all = (int*)ws + OFF_CDN;

  __shared__ uint32_t s_zw[24];
  __shared__ int s_pc[24];
  __shared__ int s_list[H1];
  __shared__ int s_n;

  if (bid < 384) {
    // -------- f-layer WG: one of 6 slices (128 neurons) of one batch row --------
    // blockIdx layout keeps all WGs of a row on the same blockIdx%8 bucket (XCD).
    const int x8 = bid & 7, q = bid >> 3;
    const int row = (q / 6)*8 + x8;
    const int s   = q % 6;
    const int k   = s*128 + t;            // this thread's neuron
    uint32_t* ring = ring_all + row*(RING*32);
    int* arr = arr_all + row*64;
    int* cdn = cdn_all + row*64;

    // deterministic reduction of the GEMM partials -> in_f[row][k]
    float inf = 0.f;
    {
      const float* part = ws + OFF_PART + row*H1 + k;
      #pragma unroll
      for (int kc = 0; kc < KSPLIT; ++kc) inf += part[(size_t)kc*(BATCH*H1)];
    }
    float vf = 0.f, iff = 0.f;

    for (int step = 0; step < SEQ; ++step) {
      float Sf = 0.f;
      if (step > 0) {
        if (t == 0) {
          while (atomic_load_acq(arr) < 6*step) {}                       // zf(step-1) published
          if (step >= RING) { while (atomic_load_acq(cdn) < step - (RING-1)) {} } // ring slot free
        }
        __syncthreads();
        const uint32_t* slot = ring + ((step-1) & (RING-1))*32;
        if (t < 24) s_zw[t] = __hip_atomic_load(slot + t, __ATOMIC_RELAXED, __HIP_MEMORY_SCOPE_AGENT);
        __syncthreads();
        if (t == 0) {
          int c = 0;
          #pragma unroll
          for (int w = 0; w < 24; ++w) { s_pc[w] = c; c += __popc(s_zw[w]); }
          s_n = c;
        }
        __syncthreads();
        if (t < 24) {
          uint32_t b = s_zw[t]; int pos = s_pc[t]; const int base = t*32;
          while (b) { const int bit = __builtin_ctz(b); s_list[pos++] = base + bit; b &= b - 1u; }
        }
        __syncthreads();
        // sparse gather: sum spiking columns of Wf_rec (rows of WfT), L2-resident
        const int n = s_n;
        const float* bp = WfT + k;
        float sA = 0.f, sB = 0.f;
        int i = 0;
        for (; i + 8 <= n; i += 8) {
          const int j0 = s_list[i+0], j1 = s_list[i+1], j2 = s_list[i+2], j3 = s_list[i+3];
          const int j4 = s_list[i+4], j5 = s_list[i+5], j6 = s_list[i+6], j7 = s_list[i+7];
          const float w0 = bp[j0*H1], w1 = bp[j1*H1], w2 = bp[j2*H1], w3 = bp[j3*H1];
          const float w4 = bp[j4*H1], w5 = bp[j5*H1], w6 = bp[j6*H1], w7 = bp[j7*H1];
          sA += w0; sB += w1; sA += w2; sB += w3;
          sA += w4; sB += w5; sA += w6; sB += w7;
        }
        for (; i < n; ++i) sA += bp[s_list[i]*H1];
        Sf = sA + sB;
      }
      // LIF update (mirrors reference op order)
      const float v_dec = vf + 0.1f*(iff - vf);
      const bool z = v_dec > 0.3f;
      vf  = z ? 0.f : v_dec;
      iff = 0.9f*iff + inf;   // i_dec + cur
      iff = iff + Sf;         // + recurrent(z_prev)
      // publish zf(step) slice
      const uint64_t m = __ballot(z);
      uint32_t* slotw = ring + (step & (RING-1))*32 + 4*s + 2*(t >> 6);
      if ((t & 63) == 0) {
        __hip_atomic_store(slotw + 0, (uint32_t)m,         __ATOMIC_RELAXED, __HIP_MEMORY_SCOPE_AGENT);
        __hip_atomic_store(slotw + 1, (uint32_t)(m >> 32), __ATOMIC_RELAXED, __HIP_MEMORY_SCOPE_AGENT);
      }
      __syncthreads();
      if (t == 0) { __threadfence(); atomicAdd(arr, 1); }
    }
  } else {
    // -------- c-layer + output WG: whole 100-neuron LIF + 101-wide LI for one row --------
    const int row = bid - 384;
    uint32_t* ring = ring_all + row*(RING*32);
    int* arr = arr_all + row*64;
    int* cdn = cdn_all + row*64;
    const float* WcT  = ws + OFF_WCT;
    const float* WcRT = ws + OFF_WCRT;
    const float* WoT  = ws + OFF_WOT;

    __shared__ uint32_t s_zcw[4];
    __shared__ int s_zcpc[4];
    __shared__ int s_zclist[H2];
    __shared__ int s_zcn;

    float vc = 0.f, ic = 0.f, vo = 0.f, io = 0.f;
    if (t == 0) s_zcn = 0;
    __syncthreads();

    for (int step = 0; step < SEQ; ++step) {
      if (t == 0) { while (atomic_load_acq(arr) < 6*(step+1)) {} }   // zf(step) published
      __syncthreads();
      const uint32_t* slot = ring + (step & (RING-1))*32;
      if (t < 24) s_zw[t] = __hip_atomic_load(slot + t, __ATOMIC_RELAXED, __HIP_MEMORY_SCOPE_AGENT);
      __syncthreads();
      if (t == 0) {
        // loads above are drained (syncthreads) -> safe to let f reuse the slot
        __hip_atomic_store(cdn, step + 1, __ATOMIC_RELEASE, __HIP_MEMORY_SCOPE_AGENT);
        int c = 0;
        #pragma unroll
        for (int w = 0; w < 24; ++w) { s_pc[w] = c; c += __popc(s_zw[w]); }
        s_n = c;
      }
      __syncthreads();
      if (t < 24) {
        uint32_t b = s_zw[t]; int pos = s_pc[t]; const int base = t*32;
        while (b) { const int bit = __builtin_ctz(b); s_list[pos++] = base + bit; b &= b - 1u; }
      }
      __syncthreads();
      const int n = s_n;
      // recurrent input from zc(step-1)
      float Sc = 0.f;
      if (t < H2) {
        const int nzc = s_zcn;
        const float* bp = WcRT + t;
        for (int i = 0; i < nzc; ++i) Sc += bp[s_zclist[i]*H2];
      }
      // feed-forward input from zf(step)
      float Sfc = 0.f;
      if (t < H2) {
        const float* bp = WcT + t;
        float sA = 0.f, sB = 0.f;
        int i = 0;
        for (; i + 8 <= n; i += 8) {
          const int j0 = s_list[i+0], j1 = s_list[i+1], j2 = s_list[i+2], j3 = s_list[i+3];
          const int j4 = s_list[i+4], j5 = s_list[i+5], j6 = s_list[i+6], j7 = s_list[i+7];
          const float w0 = bp[j0*H2], w1 = bp[j1*H2], w2 = bp[j2*H2], w3 = bp[j3*H2];
          const float w4 = bp[j4*H2], w5 = bp[j5*H2], w6 = bp[j6*H2], w7 = bp[j7*H2];
          sA += w0; sB += w1; sA += w2; sB += w3;
          sA += w4; sB += w5; sA += w6; sB += w7;
        }
        for (; i < n; ++i) sA += bp[s_list[i]*H2];
        Sfc = sA + sB;
      }
      bool zc = false;
      if (t < H2) {
        const float v_dec = vc + 0.1f*(ic - vc);
        zc = v_dec > 0.3f;
        vc = zc ? 0.f : v_dec;
        ic = 0.9f*ic + Sfc;   // i_dec + cur
        ic = ic + Sc;         // + recurrent(zc_prev)
      }
      __syncthreads();        // everyone done reading old s_zclist
      const uint64_t m = __ballot(zc);
      if ((t & 63) == 0) {
        s_zcw[2*(t>>6)+0] = (uint32_t)m;
        s_zcw[2*(t>>6)+1] = (uint32_t)(m >> 32);
      }
      __syncthreads();
      if (t == 0) {
        int c = 0;
        #pragma unroll
        for (int w = 0; w < 4; ++w) { s_zcpc[w] = c; c += __popc(s_zcw[w]); }
        s_zcn = c;
      }
      __syncthreads();
      if (t < 4) {
        uint32_t b = s_zcw[t]; int pos = s_zcpc[t]; const int base = t*32;
        while (b) { const int bit = __builtin_ctz(b); s_zclist[pos++] = base + bit; b &= b - 1u; }
      }
      __syncthreads();
      // LI output layer, cur = zc(step) @ W_out^T
      if (t < NC) {
        float So = 0.f;
        const float* bp = WoT + t;
        const int nzc = s_zcn;
        for (int i = 0; i < nzc; ++i) So += bp[s_zclist[i]*WOT_LD];
        vo = vo + 0.1f*(io - vo);   // uses OLD io
        io = 0.8f*io + So;
        out[((size_t)step*BATCH + row)*NC + t] = vo;
      }
    }
  }
}

extern "C" void kernel_launch(void* const* d_in, const int* in_sizes, int n_in,
                              void* d_out, int out_size, void* d_ws, size_t ws_size,
                              hipStream_t stream) {
  (void)in_sizes; (void)n_in; (void)out_size; (void)ws_size;
  const float* x      = (const float*)d_in[0];
  const float* Wf_in  = (const float*)d_in[1];
  const float* Wf_rec = (const float*)d_in[2];
  const float* Wc_in  = (const float*)d_in[3];
  const float* Wc_rec = (const float*)d_in[4];
  const float* W_out  = (const float*)d_in[5];
  float* out = (float*)d_out;
  float* ws  = (float*)d_ws;

  prep_kernel<<<dim3(161), dim3(256), 0, stream>>>(Wf_rec, Wc_in, Wc_rec, W_out, ws);
  gemm_inf  <<<dim3(384), dim3(256), 0, stream>>>(x, Wf_in, ws);
  scan_kernel<<<dim3(448), dim3(128), 0, stream>>>(ws, out);
}

// Round 3
// 800.435 us; speedup vs baseline: 1.8969x; 1.8969x over previous
//
#include <hip/hip_runtime.h>
#include <stdint.h>

#define SEQ    32
#define BATCH  64
#define D_IN   37632
#define H1     768
#define H2     100
#define NC     101

#define WOT_LD 104
#define RING   4

// ---- workspace layout, offsets in 4-byte words from ws base ----
// small stuff first, variable-size GEMM partials last
#define OFF_WFT   0                                        // [768][768]  WfT[j][k] = Wf_rec[k][j]
#define OFF_WCT   (OFF_WFT + H1*H1)                        // [768][100]  WcT[j][k] = Wc_in[k][j]
#define OFF_WCRT  (OFF_WCT + H1*H2)                        // [100][100]  WcRT[j][k] = Wc_rec[k][j]
#define OFF_WOT   (OFF_WCRT + H2*H2)                       // [100][104]  WoT[j][k] = W_out[k][j]
#define OFF_ARR   (((OFF_WOT + H2*WOT_LD) + 63) & ~63)     // [64][64] ints (1 used/row)
#define OFF_CDN   (OFF_ARR + 64*64)                        // [64][64] ints
#define OFF_ZF    (OFF_CDN + 64*64)                        // [64][RING][32] u32 spike ring
#define OFF_PART  (((OFF_ZF + 64*RING*32) + 255) & ~255)   // [ksplit][64][768] GEMM partials

// =============== kernel A: transposes + counter zeroing ===============
__global__ __launch_bounds__(256) void prep_kernel(
    const float* __restrict__ Wf_rec, const float* __restrict__ Wc_in,
    const float* __restrict__ Wc_rec, const float* __restrict__ W_out,
    float* __restrict__ ws)
{
  const int bid = blockIdx.x, t = threadIdx.x;
  if (bid < 144) {
    // 64x64 tiled transpose of Wf_rec (768x768)
    __shared__ float tile[64][65];
    const int tr = bid / 12, tc = bid % 12;
    for (int i = t; i < 4096; i += 256) {
      const int r = i >> 6, c = i & 63;
      tile[r][c] = Wf_rec[(tr*64 + r)*H1 + (tc*64 + c)];
    }
    __syncthreads();
    float* WfT = ws + OFF_WFT;
    for (int i = t; i < 4096; i += 256) {
      const int c = i >> 6, r = i & 63;
      WfT[(tc*64 + c)*H1 + (tr*64 + r)] = tile[r][c];
    }
  } else if (bid < 160) {
    // small transposes (L2-resident, naive)
    const int NA = H1*H2;                 // WcT elements
    const int NB = H2*H2;                 // WcRT elements
    const int NT = NA + NB + H2*NC;       // + WoT elements
    for (int idx = (bid-144)*256 + t; idx < NT; idx += 16*256) {
      if (idx < NA) {
        const int j = idx / H2, k = idx % H2;
        ws[OFF_WCT + idx] = Wc_in[k*H1 + j];
      } else if (idx < NA + NB) {
        const int q = idx - NA; const int j = q / H2, k = q % H2;
        ws[OFF_WCRT + q] = Wc_rec[k*H2 + j];
      } else {
        const int q = idx - NA - NB; const int j = q / NC, k = q % NC;
        ws[OFF_WOT + j*WOT_LD + k] = W_out[k*H2 + j];
      }
    }
  } else {
    // zero arrive / c_done counters (ws is poisoned 0xAA each launch)
    uint32_t* w = (uint32_t*)ws;
    for (int i = t; i < 64*64*2; i += 256) w[OFF_ARR + i] = 0u;
  }
}

// =============== kernel B: in_f = x @ Wf_in^T (K-split partials) ===============
// 128-wide H1 column tiles (6) x ksplit K-chunks. 256 threads: klane=t&31 covers
// 128 cols as klane+32b, blane=t>>5 covers 64 rows as blane+8a. acc[8][4].
__global__ __launch_bounds__(256) void gemm_inf(
    const float* __restrict__ x, const float* __restrict__ Wf,
    float* __restrict__ ws, int kch)
{
  const int bid = blockIdx.x;
  const int kt = bid % 6;      // which 128-col tile of H1
  const int kc = bid / 6;      // which K-chunk
  const int t  = threadIdx.x;
  const int klane = t & 31, blane = t >> 5;
  const int j0 = kc * kch;

  float acc[8][4];
  #pragma unroll
  for (int a = 0; a < 8; ++a)
    #pragma unroll
    for (int b = 0; b < 4; ++b) acc[a][b] = 0.f;

  const float4* xp[8]; const float4* wp[4];
  #pragma unroll
  for (int a = 0; a < 8; ++a)
    xp[a] = (const float4*)(x + (size_t)(blane + 8*a)*D_IN + j0);
  #pragma unroll
  for (int b = 0; b < 4; ++b)
    wp[b] = (const float4*)(Wf + (size_t)(kt*128 + klane + 32*b)*D_IN + j0);

  const int n4 = kch >> 2;
  #pragma unroll 2
  for (int j4 = 0; j4 < n4; ++j4) {
    float4 wv[4], xv[8];
    #pragma unroll
    for (int b = 0; b < 4; ++b) wv[b] = wp[b][j4];
    #pragma unroll
    for (int a = 0; a < 8; ++a) xv[a] = xp[a][j4];
    #pragma unroll
    for (int a = 0; a < 8; ++a)
      #pragma unroll
      for (int b = 0; b < 4; ++b) {
        acc[a][b] = fmaf(xv[a].x, wv[b].x, acc[a][b]);
        acc[a][b] = fmaf(xv[a].y, wv[b].y, acc[a][b]);
        acc[a][b] = fmaf(xv[a].z, wv[b].z, acc[a][b]);
        acc[a][b] = fmaf(xv[a].w, wv[b].w, acc[a][b]);
      }
  }

  float* part = ws + OFF_PART + (size_t)kc*(BATCH*H1);
  #pragma unroll
  for (int a = 0; a < 8; ++a)
    #pragma unroll
    for (int b = 0; b < 4; ++b)
      part[(blane + 8*a)*H1 + kt*128 + klane + 32*b] = acc[a][b];
}

// =============== kernel C: the 32-step scan ===============
// ALL cross-WG traffic uses RELAXED device-scope atomics (no acquire/release,
// no __threadfence): relaxed agent atomics bypass the per-XCD L2 to the
// coherent point without emitting buffer_inv / buffer_wbl2, so the L2-resident
// WfT working set survives the polling. Ordering: mask stores (device-scope)
// are drained by the s_waitcnt vmcnt(0) inside __syncthreads() before lane 0
// bumps the arrival counter.
__device__ __forceinline__ int atomic_load_rlx(const int* p) {
  return __hip_atomic_load(p, __ATOMIC_RELAXED, __HIP_MEMORY_SCOPE_AGENT);
}

__global__ __launch_bounds__(128) void scan_kernel(
    float* __restrict__ ws, float* __restrict__ out, int ksplit)
{
  const int bid = blockIdx.x, t = threadIdx.x;
  const float* WfT = ws + OFF_WFT;
  uint32_t* ring_all = (uint32_t*)ws + OFF_ZF;
  int* arr_all = (int*)ws + OFF_ARR;
  int* cdn_all = (int*)ws + OFF_CDN;

  __shared__ uint32_t s_zw[24];
  __shared__ int s_pc[24];
  __shared__ int s_list[H1];
  __shared__ int s_n;

  if (bid < 384) {
    // -------- f-layer WG: one of 6 slices (128 neurons) of one batch row --------
    // blockIdx layout keeps all WGs of a row on the same blockIdx%8 bucket (XCD).
    const int x8 = bid & 7, q = bid >> 3;
    const int row = (q / 6)*8 + x8;
    const int s   = q % 6;
    const int k   = s*128 + t;            // this thread's neuron
    uint32_t* ring = ring_all + row*(RING*32);
    int* arr = arr_all + row*64;
    int* cdn = cdn_all + row*64;

    // deterministic reduction of the GEMM partials -> in_f[row][k]
    float inf = 0.f;
    {
      const float* part = ws + OFF_PART + row*H1 + k;
      for (int kc = 0; kc < ksplit; ++kc) inf += part[(size_t)kc*(BATCH*H1)];
    }
    float vf = 0.f, iff = 0.f;

    for (int step = 0; step < SEQ; ++step) {
      float Sf = 0.f;
      if (step > 0) {
        if (t == 0) {
          while (atomic_load_rlx(arr) < 6*step) {}                       // zf(step-1) published
          if (step >= RING) { while (atomic_load_rlx(cdn) < step - (RING-1)) {} } // ring slot free
        }
        __syncthreads();
        const uint32_t* slot = ring + ((step-1) & (RING-1))*32;
        if (t < 24) s_zw[t] = __hip_atomic_load(slot + t, __ATOMIC_RELAXED, __HIP_MEMORY_SCOPE_AGENT);
        __syncthreads();
        if (t == 0) {
          int c = 0;
          #pragma unroll
          for (int w = 0; w < 24; ++w) { s_pc[w] = c; c += __popc(s_zw[w]); }
          s_n = c;
        }
        __syncthreads();
        if (t < 24) {
          uint32_t b = s_zw[t]; int pos = s_pc[t]; const int base = t*32;
          while (b) { const int bit = __builtin_ctz(b); s_list[pos++] = base + bit; b &= b - 1u; }
        }
        __syncthreads();
        // sparse gather: sum spiking columns of Wf_rec (rows of WfT), L2-resident
        const int n = s_n;
        const float* bp = WfT + k;
        float sA = 0.f, sB = 0.f;
        int i = 0;
        for (; i + 8 <= n; i += 8) {
          const int j0 = s_list[i+0], j1 = s_list[i+1], j2 = s_list[i+2], j3 = s_list[i+3];
          const int j4 = s_list[i+4], j5 = s_list[i+5], j6 = s_list[i+6], j7 = s_list[i+7];
          const float w0 = bp[j0*H1], w1 = bp[j1*H1], w2 = bp[j2*H1], w3 = bp[j3*H1];
          const float w4 = bp[j4*H1], w5 = bp[j5*H1], w6 = bp[j6*H1], w7 = bp[j7*H1];
          sA += w0; sB += w1; sA += w2; sB += w3;
          sA += w4; sB += w5; sA += w6; sB += w7;
        }
        for (; i < n; ++i) sA += bp[s_list[i]*H1];
        Sf = sA + sB;
      }
      // LIF update (mirrors reference op order)
      const float v_dec = vf + 0.1f*(iff - vf);
      const bool z = v_dec > 0.3f;
      vf  = z ? 0.f : v_dec;
      iff = 0.9f*iff + inf;   // i_dec + cur
      iff = iff + Sf;         // + recurrent(z_prev)
      // publish zf(step) slice
      const uint64_t m = __ballot(z);
      uint32_t* slotw = ring + (step & (RING-1))*32 + 4*s + 2*(t >> 6);
      if ((t & 63) == 0) {
        __hip_atomic_store(slotw + 0, (uint32_t)m,         __ATOMIC_RELAXED, __HIP_MEMORY_SCOPE_AGENT);
        __hip_atomic_store(slotw + 1, (uint32_t)(m >> 32), __ATOMIC_RELAXED, __HIP_MEMORY_SCOPE_AGENT);
      }
      __syncthreads();  // drains vmcnt for ALL waves before lane 0 signals
      if (t == 0) __hip_atomic_fetch_add(arr, 1, __ATOMIC_RELAXED, __HIP_MEMORY_SCOPE_AGENT);
    }
  } else {
    // -------- c-layer + output WG: whole 100-neuron LIF + 101-wide LI for one row --------
    const int row = bid - 384;
    uint32_t* ring = ring_all + row*(RING*32);
    int* arr = arr_all + row*64;
    int* cdn = cdn_all + row*64;
    const float* WcT  = ws + OFF_WCT;
    const float* WcRT = ws + OFF_WCRT;
    const float* WoT  = ws + OFF_WOT;

    __shared__ uint32_t s_zcw[4];
    __shared__ int s_zcpc[4];
    __shared__ int s_zclist[H2];
    __shared__ int s_zcn;

    float vc = 0.f, ic = 0.f, vo = 0.f, io = 0.f;
    if (t == 0) s_zcn = 0;
    __syncthreads();

    for (int step = 0; step < SEQ; ++step) {
      if (t == 0) { while (atomic_load_rlx(arr) < 6*(step+1)) {} }   // zf(step) published
      __syncthreads();
      const uint32_t* slot = ring + (step & (RING-1))*32;
      if (t < 24) s_zw[t] = __hip_atomic_load(slot + t, __ATOMIC_RELAXED, __HIP_MEMORY_SCOPE_AGENT);
      __syncthreads();  // mask loads drained -> safe to free the slot
      if (t == 0) {
        __hip_atomic_store(cdn, step + 1, __ATOMIC_RELAXED, __HIP_MEMORY_SCOPE_AGENT);
        int c = 0;
        #pragma unroll
        for (int w = 0; w < 24; ++w) { s_pc[w] = c; c += __popc(s_zw[w]); }
        s_n = c;
      }
      __syncthreads();
      if (t < 24) {
        uint32_t b = s_zw[t]; int pos = s_pc[t]; const int base = t*32;
        while (b) { const int bit = __builtin_ctz(b); s_list[pos++] = base + bit; b &= b - 1u; }
      }
      __syncthreads();
      const int n = s_n;
      // recurrent input from zc(step-1)
      float Sc = 0.f;
      if (t < H2) {
        const int nzc = s_zcn;
        const float* bp = WcRT + t;
        for (int i = 0; i < nzc; ++i) Sc += bp[s_zclist[i]*H2];
      }
      // feed-forward input from zf(step)
      float Sfc = 0.f;
      if (t < H2) {
        const float* bp = WcT + t;
        float sA = 0.f, sB = 0.f;
        int i = 0;
        for (; i + 8 <= n; i += 8) {
          const int j0 = s_list[i+0], j1 = s_list[i+1], j2 = s_list[i+2], j3 = s_list[i+3];
          const int j4 = s_list[i+4], j5 = s_list[i+5], j6 = s_list[i+6], j7 = s_list[i+7];
          const float w0 = bp[j0*H2], w1 = bp[j1*H2], w2 = bp[j2*H2], w3 = bp[j3*H2];
          const float w4 = bp[j4*H2], w5 = bp[j5*H2], w6 = bp[j6*H2], w7 = bp[j7*H2];
          sA += w0; sB += w1; sA += w2; sB += w3;
          sA += w4; sB += w5; sA += w6; sB += w7;
        }
        for (; i < n; ++i) sA += bp[s_list[i]*H2];
        Sfc = sA + sB;
      }
      bool zc = false;
      if (t < H2) {
        const float v_dec = vc + 0.1f*(ic - vc);
        zc = v_dec > 0.3f;
        vc = zc ? 0.f : v_dec;
        ic = 0.9f*ic + Sfc;   // i_dec + cur
        ic = ic + Sc;         // + recurrent(zc_prev)
      }
      __syncthreads();        // everyone done reading old s_zclist
      const uint64_t m = __ballot(zc);
      if ((t & 63) == 0) {
        s_zcw[2*(t>>6)+0] = (uint32_t)m;
        s_zcw[2*(t>>6)+1] = (uint32_t)(m >> 32);
      }
      __syncthreads();
      if (t == 0) {
        int c = 0;
        #pragma unroll
        for (int w = 0; w < 4; ++w) { s_zcpc[w] = c; c += __popc(s_zcw[w]); }
        s_zcn = c;
      }
      __syncthreads();
      if (t < 4) {
        uint32_t b = s_zcw[t]; int pos = s_zcpc[t]; const int base = t*32;
        while (b) { const int bit = __builtin_ctz(b); s_zclist[pos++] = base + bit; b &= b - 1u; }
      }
      __syncthreads();
      // LI output layer, cur = zc(step) @ W_out^T
      if (t < NC) {
        float So = 0.f;
        const float* bp = WoT + t;
        const int nzc = s_zcn;
        for (int i = 0; i < nzc; ++i) So += bp[s_zclist[i]*WOT_LD];
        vo = vo + 0.1f*(io - vo);   // uses OLD io
        io = 0.8f*io + So;
        out[((size_t)step*BATCH + row)*NC + t] = vo;
      }
    }
  }
}

extern "C" void kernel_launch(void* const* d_in, const int* in_sizes, int n_in,
                              void* d_out, int out_size, void* d_ws, size_t ws_size,
                              hipStream_t stream) {
  (void)in_sizes; (void)n_in; (void)out_size;
  const float* x      = (const float*)d_in[0];
  const float* Wf_in  = (const float*)d_in[1];
  const float* Wf_rec = (const float*)d_in[2];
  const float* Wc_in  = (const float*)d_in[3];
  const float* Wc_rec = (const float*)d_in[4];
  const float* W_out  = (const float*)d_in[5];
  float* out = (float*)d_out;
  float* ws  = (float*)d_ws;

  // pick K-split by available scratch (96 needs ~21.7 MB, 32 needs ~9.1 MB)
  const size_t need96 = ((size_t)OFF_PART + (size_t)96*BATCH*H1) * 4u;
  const int ksplit = (ws_size >= need96) ? 96 : 32;
  const int kch = D_IN / ksplit;

  prep_kernel<<<dim3(161), dim3(256), 0, stream>>>(Wf_rec, Wc_in, Wc_rec, W_out, ws);
  gemm_inf  <<<dim3(6*ksplit), dim3(256), 0, stream>>>(x, Wf_in, ws, kch);
  scan_kernel<<<dim3(448), dim3(128), 0, stream>>>(ws, out, ksplit);
}